// Round 6
// baseline (65.285 us; speedup 1.0000x reference)
//
#include <hip/hip_runtime.h>

typedef __attribute__((ext_vector_type(8))) short bf16x8;
typedef __attribute__((ext_vector_type(16))) float f32x16;

#define C2LE 2.8853900817779268f     // 2*log2(e)
#define NEG2C (-5.7707801635558537f) // -2*C2LE

static __device__ __forceinline__ unsigned cvt_pk_bf16(float a, float b) {
    unsigned r;
    asm("v_cvt_pk_bf16_f32 %0, %1, %2" : "=v"(r) : "v"(a), "v"(b));
    return r;
}
static __device__ __forceinline__ float exp2_r(float x) {
    float r; asm("v_exp_f32 %0, %1" : "=v"(r) : "v"(x)); return r;
}
static __device__ __forceinline__ float rcp_r(float x) {
    float r; asm("v_rcp_f32 %0, %1" : "=v"(r) : "v"(x)); return r;
}
// Integer-magic reciprocal + 1 Newton: ~3.4e-3 max rel err, always <= 1/d.
// Full-rate VALU (6 cyc) vs v_rcp (16 cyc trans).
static __device__ __forceinline__ float mrcp(float d) {
    float r0 = __uint_as_float(0x7EF127EAu - __float_as_uint(d));
    return r0 * fmaf(-d, r0, 2.0f);
}
static __device__ __forceinline__ bf16x8 mk_frag(unsigned a, unsigned b, unsigned c, unsigned d) {
    union { unsigned u[4]; bf16x8 v; } x;
    x.u[0]=a; x.u[1]=b; x.u[2]=c; x.u[3]=d; return x.v;
}

// f(e,g): L1 = MFMA (A = c*W1 hi/lo split, B = raw e,g hi/lo split),
// sigmoid r=1/(1+2^x): L1 bank via magic-rcp (feeds bf16 anyway),
// L2 = MFMA with A' = -2c*W2^T (tanh folded),
// L3 bank via quad-batched trans rcp, then VALU dot (tanh folded).
static __device__ __forceinline__ float mlp_f(float e, float g,
        bf16x8 A1, const f32x16& cb1v,
        bf16x8 A20, bf16x8 A21, const f32x16& cb2v,
        const f32x16& w3m, float o0)
{
    // ---- layer 1 B-operand: k-slots [e_hi, e_lo, e_hi, g_hi, g_lo, g_hi, 0, 0]
    unsigned Ph = cvt_pk_bf16(e, g);
    float ehf = __uint_as_float(Ph << 16);
    float ghf = __uint_as_float(Ph & 0xffff0000u);
    unsigned Pl = cvt_pk_bf16(e - ehf, g - ghf);
    unsigned eh = Ph & 0xffffu, gh = Ph >> 16;
    unsigned el = Pl & 0xffffu, gl = Pl >> 16;
    unsigned w0 = eh | (el << 16);
    unsigned w1 = eh | (gh << 16);
    unsigned w2 = gl | (gh << 16);
    auto s0 = __builtin_amdgcn_permlane32_swap((int)w0, 0, false, false);
    auto s1 = __builtin_amdgcn_permlane32_swap((int)w1, 0, false, false);
    auto s2 = __builtin_amdgcn_permlane32_swap((int)w2, 0, false, false);
    bf16x8 Bg1 = mk_frag((unsigned)s0[0], (unsigned)s1[0], (unsigned)s2[0], 0u);
    bf16x8 Bg2 = mk_frag((unsigned)s0[1], (unsigned)s1[1], (unsigned)s2[1], 0u);
    f32x16 d1 = __builtin_amdgcn_mfma_f32_32x32x16_bf16(A1, Bg1, cb1v, 0, 0, 0);
    f32x16 d2 = __builtin_amdgcn_mfma_f32_32x32x16_bf16(A1, Bg2, cb1v, 0, 0, 0);

    // ---- sigmoid bank 1: r = mrcp(1 + 2^x), pack to bf16 pairs
    unsigned P[8], Q[8];
#pragma unroll
    for (int m = 0; m < 8; ++m) {
        float ra = mrcp(exp2_r(d1[2*m])   + 1.0f);
        float rb = mrcp(exp2_r(d1[2*m+1]) + 1.0f);
        P[m] = cvt_pk_bf16(ra, rb);
        float rc = mrcp(exp2_r(d2[2*m])   + 1.0f);
        float rd = mrcp(exp2_r(d2[2*m+1]) + 1.0f);
        Q[m] = cvt_pk_bf16(rc, rd);
    }

    // ---- layer 2: acc = A' @ r + cb2v
    f32x16 a1 = cb2v, a2 = cb2v;
    {
        auto u02 = __builtin_amdgcn_permlane32_swap((int)P[0], (int)P[2], false, false);
        auto u13 = __builtin_amdgcn_permlane32_swap((int)P[1], (int)P[3], false, false);
        bf16x8 Bq = mk_frag((unsigned)u02[0], (unsigned)u13[0], (unsigned)u02[1], (unsigned)u13[1]);
        a1 = __builtin_amdgcn_mfma_f32_32x32x16_bf16(A20, Bq, a1, 0, 0, 0);
        auto v02 = __builtin_amdgcn_permlane32_swap((int)P[4], (int)P[6], false, false);
        auto v13 = __builtin_amdgcn_permlane32_swap((int)P[5], (int)P[7], false, false);
        bf16x8 Br = mk_frag((unsigned)v02[0], (unsigned)v13[0], (unsigned)v02[1], (unsigned)v13[1]);
        a1 = __builtin_amdgcn_mfma_f32_32x32x16_bf16(A21, Br, a1, 0, 0, 0);
    }
    {
        auto u02 = __builtin_amdgcn_permlane32_swap((int)Q[0], (int)Q[2], false, false);
        auto u13 = __builtin_amdgcn_permlane32_swap((int)Q[1], (int)Q[3], false, false);
        bf16x8 Bq = mk_frag((unsigned)u02[0], (unsigned)u13[0], (unsigned)u02[1], (unsigned)u13[1]);
        a2 = __builtin_amdgcn_mfma_f32_32x32x16_bf16(A20, Bq, a2, 0, 0, 0);
        auto v02 = __builtin_amdgcn_permlane32_swap((int)Q[4], (int)Q[6], false, false);
        auto v13 = __builtin_amdgcn_permlane32_swap((int)Q[5], (int)Q[7], false, false);
        bf16x8 Br = mk_frag((unsigned)v02[0], (unsigned)v13[0], (unsigned)v02[1], (unsigned)v13[1]);
        a2 = __builtin_amdgcn_mfma_f32_32x32x16_bf16(A21, Br, a2, 0, 0, 0);
    }

    // ---- layer 3: o = o0 + sum w3m[r]*sig(acc[r]); quad-batched trans rcp
    float pA = 0.0f, pB = 0.0f;
#pragma unroll
    for (int q = 0; q < 4; ++q) {
        {
            float e0 = exp2_r(a1[4*q])   + 1.0f;
            float e1 = exp2_r(a1[4*q+1]) + 1.0f;
            float e2 = exp2_r(a1[4*q+2]) + 1.0f;
            float e3 = exp2_r(a1[4*q+3]) + 1.0f;
            float m01 = e0 * e1, m012 = m01 * e2, m0123 = m012 * e3;
            float R   = rcp_r(m0123);
            float r3  = R * m012;
            float R3  = R * e3;
            float r2  = R3 * m01;
            float R32 = R3 * e2;
            float r1  = R32 * e0;
            float r0  = R32 * e1;
            pA = fmaf(w3m[4*q], r0, fmaf(w3m[4*q+1], r1,
                 fmaf(w3m[4*q+2], r2, fmaf(w3m[4*q+3], r3, pA))));
        }
        {
            float e0 = exp2_r(a2[4*q])   + 1.0f;
            float e1 = exp2_r(a2[4*q+1]) + 1.0f;
            float e2 = exp2_r(a2[4*q+2]) + 1.0f;
            float e3 = exp2_r(a2[4*q+3]) + 1.0f;
            float m01 = e0 * e1, m012 = m01 * e2, m0123 = m012 * e3;
            float R   = rcp_r(m0123);
            float r3  = R * m012;
            float R3  = R * e3;
            float r2  = R3 * m01;
            float R32 = R3 * e2;
            float r1  = R32 * e0;
            float r0  = R32 * e1;
            pB = fmaf(w3m[4*q], r0, fmaf(w3m[4*q+1], r1,
                 fmaf(w3m[4*q+2], r2, fmaf(w3m[4*q+3], r3, pB))));
        }
    }
    auto c = __builtin_amdgcn_permlane32_swap(__float_as_int(pA), __float_as_int(pB), false, false);
    float o = o0 + __int_as_float(c[0]) + __int_as_float(c[1]);
    return __logf(1.0f + __expf(o));
}

__global__ __launch_bounds__(256, 1) void gamma_rk4_mfma(
        const float4* __restrict__ inp, const float* __restrict__ gamma,
        const float* __restrict__ W1, const float* __restrict__ b1,
        const float* __restrict__ W2, const float* __restrict__ b2,
        const float* __restrict__ W3, const float* __restrict__ b3,
        float* __restrict__ out, int B)
{
    int idx  = blockIdx.x * 256 + threadIdx.x;
    int lane = threadIdx.x & 63;
    int hi   = lane >> 5;
    int arow = lane & 31;

    // L1 A-frag: a = c*W1[0][j], b = c*W1[1][j], hi/lo split;
    // k-slots [a_hi, a_hi, a_lo, b_hi, b_hi, b_lo, 0, 0]; hi lanes zero.
    bf16x8 A1;
    {
        float ca = C2LE * W1[arow];
        float cb = C2LE * W1[32 + arow];
        unsigned Wh = cvt_pk_bf16(ca, cb);
        float ah = __uint_as_float(Wh << 16);
        float bh = __uint_as_float(Wh & 0xffff0000u);
        unsigned Wl = cvt_pk_bf16(ca - ah, cb - bh);
        unsigned ahi = Wh & 0xffffu, bhi = Wh >> 16;
        unsigned alo = Wl & 0xffffu, blo = Wl >> 16;
        A1 = hi ? mk_frag(0u, 0u, 0u, 0u)
                : mk_frag(ahi | (ahi << 16), alo | (bhi << 16), bhi | (blo << 16), 0u);
    }
    // L2 A' = -2c * W2^T in bf16 (two K=16 chunks)
    bf16x8 A2[2];
#pragma unroll
    for (int s = 0; s < 2; ++s) {
        unsigned w[4];
#pragma unroll
        for (int m = 0; m < 4; ++m) {
            float a = NEG2C * W2[(16*s + 8*hi + 2*m    ) * 32 + arow];
            float b = NEG2C * W2[(16*s + 8*hi + 2*m + 1) * 32 + arow];
            w[m] = cvt_pk_bf16(a, b);
        }
        A2[s] = mk_frag(w[0], w[1], w[2], w[3]);
    }
    // per-reg row map: row = (r&3) + 8*(r>>2) + 4*hi
    f32x16 cb1v, cb2v, w3m;
    float wsum = 0.0f;
#pragma unroll
    for (int r = 0; r < 16; ++r) {
        int row = (r & 3) + 8 * (r >> 2) + 4 * hi;
        cb1v[r] = C2LE * b1[row];
        cb2v[r] = C2LE * b2[row];
        float w3 = W3[row];
        w3m[r] = -2.0f * w3;
        wsum  += w3;
    }
    // cb2v += c*colsum(W2) via MFMA with B = -0.5 (exact in bf16)
    {
        unsigned nh = 0xBF00BF00u;
        bf16x8 negh = mk_frag(nh, nh, nh, nh);
        cb2v = __builtin_amdgcn_mfma_f32_32x32x16_bf16(A2[0], negh, cb2v, 0, 0, 0);
        cb2v = __builtin_amdgcn_mfma_f32_32x32x16_bf16(A2[1], negh, cb2v, 0, 0, 0);
    }
    auto sw = __builtin_amdgcn_permlane32_swap(__float_as_int(wsum), __float_as_int(wsum), false, false);
    float o0 = b3[0] + __int_as_float(sw[0]) + __int_as_float(sw[1]);

    if (idx >= B) return;
    float4 v  = inp[idx];                 // eps_n, eps_half, eps_one, dt
    float g0  = gamma[idx];

    float k1 = v.w * mlp_f(v.x, g0, A1, cb1v, A2[0], A2[1], cb2v, w3m, o0) * (v.x - g0);
    float g1 = fmaf(0.5f, k1, g0);
    float k2 = v.w * mlp_f(v.y, g1, A1, cb1v, A2[0], A2[1], cb2v, w3m, o0) * (v.y - g1);
    float g2 = fmaf(0.5f, k2, g0);
    float k3 = v.w * mlp_f(v.y, g2, A1, cb1v, A2[0], A2[1], cb2v, w3m, o0) * (v.y - g2);
    float g3 = g0 + k3;
    float k4 = v.w * mlp_f(v.z, g3, A1, cb1v, A2[0], A2[1], cb2v, w3m, o0) * (v.z - g3);

    out[idx] = g0 + (k1 + 2.0f * (k2 + k3) + k4) * (1.0f / 6.0f);
}

extern "C" void kernel_launch(void* const* d_in, const int* in_sizes, int n_in,
                              void* d_out, int out_size, void* d_ws, size_t ws_size,
                              hipStream_t stream) {
    const float4* inp   = (const float4*)d_in[0];
    const float*  gamma = (const float*)d_in[1];
    const float*  W1    = (const float*)d_in[2];
    const float*  b1    = (const float*)d_in[3];
    const float*  W2    = (const float*)d_in[4];
    const float*  b2    = (const float*)d_in[5];
    const float*  W3    = (const float*)d_in[6];
    const float*  b3    = (const float*)d_in[7];
    float* out = (float*)d_out;

    int B = in_sizes[1];
    int block = 256;
    int grid = (B + block - 1) / block;
    gamma_rk4_mfma<<<grid, block, 0, stream>>>(inp, gamma, W1, b1, W2, b2,
                                               W3, b3, out, B);
}